// Round 1
// 78.203 us; speedup vs baseline: 1.0293x; 1.0293x over previous
//
#include <hip/hip_runtime.h>
#include <math.h>

#define NATOMS   2000
#define KNBR     24
#define HCAP     192    // cap for d<=5.1 hits per atom (~56 expected, Poisson tail safe)
#define ACAP     64     // cap for d<=3.5 candidates (~18 expected; proven <=64 exact)
#define BLOCK    256
#define NFEAT    1904.0f   // 7*16 + 28*64

__device__ __forceinline__ float wave_reduce_add(float v) {
    #pragma unroll
    for (int off = 32; off > 0; off >>= 1) v += __shfl_down(v, off, 64);
    return v;
}

// One block per atom i. Positions (24 KB) are read through L1 (fully resident).
__global__ __launch_bounds__(BLOCK) void aev_block_kernel(
        const float* __restrict__ pos, float* __restrict__ partial) {
    constexpr float RCR = 5.1f, RCA = 3.5f;
    constexpr float ETA_R = 19.7f, ZETA = 14.1f, ETA_A = 12.5f;
    constexpr float PI = 3.14159265358979323846f;

    __shared__ float hd2[HCAP];
    __shared__ int   hj[HCAP];
    __shared__ float ad[ACAP];
    __shared__ int   aj[ACAP];
    __shared__ int   s_hcnt, s_acnt;
    __shared__ float nbx[KNBR], nby[KNBR], nbz[KNBR], nbd[KNBR], nbfc[KNBR];
    __shared__ float red[BLOCK / 64];

    const int tid  = threadIdx.x;
    const int i    = blockIdx.x;
    const int lane = tid & 63;

    if (tid == 0) { s_hcnt = 0; s_acnt = 0; }
    __syncthreads();

    // i is wave-uniform -> scalar loads.
    const float xi = pos[3 * i + 0], yi = pos[3 * i + 1], zi = pos[3 * i + 2];

    // --- Phase 1a: 2 atoms per lane per iteration; 3x float2 loads (8B-aligned
    // since j0 is even -> byte offset 12*j0 = 24*(j0/2)); dual-ballot compact ---
    for (int jb = 0; jb < NATOMS; jb += 2 * BLOCK) {
        int j0 = jb + 2 * tid;                       // even
        int jc = (j0 <= NATOMS - 2) ? j0 : (NATOMS - 2);
        const float2* p2 = (const float2*)(pos + 3 * jc);
        float2 v0 = p2[0];   // x0 y0
        float2 v1 = p2[1];   // z0 x1
        float2 v2 = p2[2];   // y1 z1
        float dx0 = v0.x - xi, dy0 = v0.y - yi, dz0 = v1.x - zi;
        float dx1 = v1.y - xi, dy1 = v2.x - yi, dz1 = v2.y - zi;
        float d20 = dx0 * dx0 + dy0 * dy0 + dz0 * dz0;
        float d21 = dx1 * dx1 + dy1 * dy1 + dz1 * dz1;
        // clamped lanes (j0 >= NATOMS) fail the j0 < NATOMS test -> no false hits
        bool hit0 = (j0 < NATOMS)     && (j0 != i)       && (d20 <= RCR * RCR);
        bool hit1 = (j0 + 1 < NATOMS) && (j0 + 1 != i)   && (d21 <= RCR * RCR);
        unsigned long long m0 = __ballot(hit0);
        unsigned long long m1 = __ballot(hit1);
        int nw = __popcll(m0) + __popcll(m1);
        int base = 0;
        if (lane == 0 && nw) base = atomicAdd(&s_hcnt, nw);
        base = __shfl(base, 0, 64);
        unsigned long long ltmask = (1ull << lane) - 1ull;
        if (hit0) {
            int idx = base + __popcll(m0 & ltmask);
            if (idx < HCAP) { hd2[idx] = d20; hj[idx] = j0; }
        }
        if (hit1) {
            int idx = base + __popcll(m0) + __popcll(m1 & ltmask);
            if (idx < HCAP) { hd2[idx] = d21; hj[idx] = j0 + 1; }
        }
    }
    __syncthreads();

    // --- Phase 1b: dense radial body over ~56 hits (one iteration) ---
    float psum = 0.0f;
    int hcnt = min(s_hcnt, HCAP);
    for (int c = tid; c < hcnt; c += BLOCK) {
        float d2 = hd2[c];
        float d  = sqrtf(d2);
        float fc = 0.5f * __cosf(d * (PI / RCR)) + 0.5f;
        float s  = 0.0f;
        #pragma unroll
        for (int r = 0; r < 16; r++) {
            float t = d - (0.8f + 0.26875f * (float)r);
            s += __expf(-ETA_R * t * t);
        }
        psum += 0.25f * fc * s;
        if (d2 <= RCA * RCA) {
            int a = atomicAdd(&s_acnt, 1);
            if (a < ACAP) { ad[a] = d; aj[a] = hj[c]; }
        }
    }
    __syncthreads();

    // --- Phase 2: rank-select min(cnt,24) nearest (stable: tie-break on j) ---
    int cnt = min(s_acnt, ACAP);
    int M   = min(cnt, KNBR);
    if (tid < cnt) {
        float dt = ad[tid];
        int   jt = aj[tid];
        int rank = 0;
        for (int u = 0; u < cnt; u++) {
            float du = ad[u];
            if (du < dt || (du == dt && aj[u] < jt)) rank++;
        }
        if (rank < KNBR) {
            nbx[rank]  = pos[3 * jt + 0] - xi;
            nby[rank]  = pos[3 * jt + 1] - yi;
            nbz[rank]  = pos[3 * jt + 2] - zi;
            nbd[rank]  = dt;
            nbfc[rank] = 0.5f * __cosf(dt * (PI / RCA)) + 0.5f;
        }
    }
    __syncthreads();

    // --- Phase 3: angular sum over unordered pairs a<b of selected set ---
    // cos(theta - shz) expanded: ca*cos(shz) + sa*sin(shz); sa = sqrt(1-ca^2)
    // is safe since |ca| <= 0.95. Removes acosf + 8x __cosf per pair.
    int npairs = M * (M - 1) / 2;
    const float tM = 2.0f * (float)M - 1.0f;
    for (int p = tid; p < npairs; p += BLOCK) {
        // closed-form row decode with integer fix-up (fp-rounding safe)
        float fp = (float)p;
        int a = (int)floorf(0.5f * (tM - sqrtf(fmaxf(tM * tM - 8.0f * fp, 0.0f))));
        a = a < 0 ? 0 : (a > M - 2 ? M - 2 : a);
        int S = (a * (2 * M - 1 - a)) >> 1;           // pairs before row a
        while (S > p)                { a--; S = (a * (2 * M - 1 - a)) >> 1; }
        while (S + (M - 1 - a) <= p) { S += M - 1 - a; a++; }
        int b = a + 1 + (p - S);

        float dot = nbx[a] * nbx[b] + nby[a] * nby[b] + nbz[a] * nbz[b];
        float ra = nbd[a], rb = nbd[b];
        float ca = 0.95f * dot / (ra * rb);
        float sa = sqrtf(fmaxf(1.0f - ca * ca, 0.0f));

        const float CZ[8] = {  0.92387953f,  0.38268343f, -0.38268343f, -0.92387953f,
                              -0.92387953f, -0.38268343f,  0.38268343f,  0.92387953f };
        const float SZ[8] = {  0.38268343f,  0.92387953f,  0.92387953f,  0.38268343f,
                              -0.38268343f, -0.92387953f, -0.92387953f, -0.38268343f };
        float f1 = 0.0f;
        #pragma unroll
        for (int z = 0; z < 8; z++) {
            float c = 0.5f + 0.5f * (ca * CZ[z] + sa * SZ[z]);
            f1 += __powf(fmaxf(c, 1e-20f), ZETA);
        }
        float avg = 0.5f * (ra + rb);
        float f2  = 0.0f;
        #pragma unroll
        for (int s8 = 0; s8 < 8; s8++) {
            float t = avg - (0.8f + 0.3375f * (float)s8);
            f2 += __expf(-ETA_A * t * t);
        }
        psum += 2.0f * nbfc[a] * nbfc[b] * f1 * f2;
    }

    // --- Block reduction; plain store (no atomic, no zero-init needed) ---
    psum = wave_reduce_add(psum);
    if (lane == 0) red[tid >> 6] = psum;
    __syncthreads();
    if (tid == 0) {
        float total = 0.0f;
        #pragma unroll
        for (int w = 0; w < BLOCK / 64; w++) total += red[w];
        partial[i] = total;
    }
}

__global__ __launch_bounds__(BLOCK) void finalize_kernel(
        const float* __restrict__ partial, float* __restrict__ out) {
    __shared__ float red[BLOCK / 64];
    const int tid = threadIdx.x;
    float v = 0.0f;
    for (int c = tid; c < NATOMS; c += BLOCK) v += partial[c];
    v = wave_reduce_add(v);
    if ((tid & 63) == 0) red[tid >> 6] = v;
    __syncthreads();
    if (tid == 0) {
        float total = 0.0f;
        #pragma unroll
        for (int w = 0; w < BLOCK / 64; w++) total += red[w];
        out[0] = total / ((float)NATOMS * NFEAT);
    }
}

extern "C" void kernel_launch(void* const* d_in, const int* in_sizes, int n_in,
                              void* d_out, int out_size, void* d_ws, size_t ws_size,
                              hipStream_t stream) {
    // d_in[0]: species (int32) -- irrelevant to the mean (scatter bins are a
    // partition; the final mean sums over all bins). d_in[1]: positions (f32 Nx3).
    const float* pos = (const float*)d_in[1];
    float* partial = (float*)d_ws;   // NATOMS floats; written (not accumulated), no init needed

    aev_block_kernel<<<NATOMS, BLOCK, 0, stream>>>(pos, partial);
    finalize_kernel<<<1, BLOCK, 0, stream>>>(partial, (float*)d_out);
}